// Round 13
// baseline (68.535 us; speedup 1.0000x reference)
//
#include <hip/hip_runtime.h>
#include <hip/hip_cooperative_groups.h>
#include <cstddef>

namespace cg = cooperative_groups;

// Problem constants (from reference)
constexpr int Bn = 64;     // batch
constexpr int In = 2048;   // input capsules
constexpr int Dk = 8;      // input dim
constexpr int Kc = 16;     // output capsules
constexpr int En = 16;     // output dim
constexpr float EPS = 1e-7f;

// Decomposition: block = (p, g) tile of 8 i's x 32 batches, 4 waves; wave
// owns 8 batches x all 8 i's -> disjoint outputs, barrier-free iter.
// WHY 8 batches/wave: W-traffic = waves x 64KB/iter; R12 (4 b/wave, 4096
// waves) pushed 256 MB/iter through L2 (~7.4 us/XCD) -- the measured iter
// bottleneck. 8 b/wave halves it. 512 blocks = 2/CU = 2 waves/SIMD, so the
// ~130-VGPR live set (acc[8]+vb[8]+w[8]) is spill-safe without any cap.
constexpr int IB   = 8;            // i's per block
constexpr int P    = In / IB;      // 256 i-chunks
constexpr int BSET = 32;           // batches per block (8 per wave)
constexpr int NBG  = Bn / BSET;    // 2 batch groups
constexpr int BLOCKS = P * NBG;    // 512
constexpr int THREADS = 256;       // 4 waves
constexpr int PPX  = P / 8;        // 32 p-chunks per XCD (2 MB of W < 4 MB L2)

// DPP cross-lane add on the VALU pipe (no LDS-pipe traffic).
// ctrl: 0xB1 = quad_perm xor1, 0x4E = quad_perm xor2, 0x124/0x128 = row_ror 4/8
template<int CTRL>
__device__ __forceinline__ float dpp_add(float v) {
    int r = __builtin_amdgcn_update_dpp(0, __float_as_int(v), CTRL, 0xF, 0xF, true);
    return v + __int_as_float(r);
}

// One routing iteration for a (p, g) tile. x tile staged in smemx[0,2048) as
// [bl][il][d]. Wave wv handles batches bw..bw+7 across all 8 i's; acc[8] =
// 32 VGPR, vb[8] = 32 VGPR, w[8] = 32 VGPR -- all statically indexed
// (R4/R5 lesson). Barrier-free; 8 plain float4 stores per lane at the end.
template<bool UNIFORM>
__device__ __forceinline__ void iter_body(const float* __restrict__ smemx,
        const float* __restrict__ W, const float* __restrict__ vsg,
        float* __restrict__ partial, int p, int b0, int i0, int t)
{
    const int lane = t & 63;
    const int wv   = t >> 6;                // 0..3
    const int k    = lane >> 2;             // output capsule
    const int e4   = (lane & 3) << 2;       // first of 4 output dims
    const int bw   = b0 + (wv << 3);        // this wave's first batch (8 each)

    float4 vb[8];
    if (!UNIFORM) {
        #pragma unroll
        for (int b4 = 0; b4 < 8; ++b4)
            vb[b4] = *(const float4*)(vsg + ((bw + b4) << 8) + k * 16 + e4);
    }

    float4 acc[8];
    #pragma unroll
    for (int b4 = 0; b4 < 8; ++b4) acc[b4] = make_float4(0.f, 0.f, 0.f, 0.f);

    #pragma unroll 1
    for (int ii = 0; ii < IB; ++ii) {
        const int i = i0 + ii;
        const float* wp = W + (size_t)i * (Kc * Dk * En) + k * (Dk * En) + e4;
        float4 w[8];
        #pragma unroll
        for (int d = 0; d < 8; ++d) w[d] = *(const float4*)(wp + d * En);

        #pragma unroll
        for (int b4 = 0; b4 < 8; ++b4) {
            const int bl = (wv << 3) + b4;
            const float* xp = smemx + (((bl << 3) + ii) << 3);  // [bl][ii][*]
            const float4 x0 = *(const float4*)xp;
            const float4 x1 = *(const float4*)(xp + 4);
            const float xs8[8] = {x0.x, x0.y, x0.z, x0.w, x1.x, x1.y, x1.z, x1.w};

            float4 uh = make_float4(0.f, 0.f, 0.f, 0.f);
            #pragma unroll
            for (int d = 0; d < 8; ++d) {
                uh.x = fmaf(xs8[d], w[d].x, uh.x);
                uh.y = fmaf(xs8[d], w[d].y, uh.y);
                uh.z = fmaf(xs8[d], w[d].z, uh.z);
                uh.w = fmaf(xs8[d], w[d].w, uh.w);
            }

            if (UNIFORM) {
                acc[b4].x += uh.x; acc[b4].y += uh.y;
                acc[b4].z += uh.z; acc[b4].w += uh.w;
            } else {
                float tt = uh.x * vb[b4].x + uh.y * vb[b4].y
                         + uh.z * vb[b4].z + uh.w * vb[b4].w;
                tt = dpp_add<0xB1>(tt);           // e-reduce: quad xor 1
                tt = dpp_add<0x4E>(tt);           // e-reduce: quad xor 2
                const float pe = __expf(tt);      // no max-sub: |tt| small
                float den = dpp_add<0x124>(pe);   // k-sum in row: ror 4
                den = dpp_add<0x128>(den);        // k-sum in row: ror 8
                den += __shfl_xor(den, 16);       // cross-row
                den += __shfl_xor(den, 32);
                const float c = pe * __builtin_amdgcn_rcpf(den);
                acc[b4].x = fmaf(c, uh.x, acc[b4].x);
                acc[b4].y = fmaf(c, uh.y, acc[b4].y);
                acc[b4].z = fmaf(c, uh.z, acc[b4].z);
                acc[b4].w = fmaf(c, uh.w, acc[b4].w);
            }
        }
    }

    #pragma unroll
    for (int b4 = 0; b4 < 8; ++b4)
        *(float4*)(partial + ((size_t)(bw + b4) * P + p) * 256 + k * 16 + e4) = acc[b4];
}

// Sum the P=256 partials, squash, optional vprev add. rb = 0..255:
// b = rb>>2, element-quarter q = rb&3; 4 p-groups of 64 p's, combined in LDS.
__device__ __forceinline__ void reduce_phase(float* red,
        const float* __restrict__ partial, float scale,
        const float* __restrict__ vprev, float* __restrict__ vout, int rb, int t)
{
    const int b  = rb >> 2;
    const int q  = rb & 3;
    const int t4 = t & 63;
    const int pg = t >> 6;
    const int el = (q << 6) + t4;           // element 0..255 (= k*16+e)
    const float* pp = partial + (size_t)b * (P * 256) + ((pg << 6) * 256) + el;

    float s0 = 0.f, s1 = 0.f, s2 = 0.f, s3 = 0.f;
    #pragma unroll 4
    for (int j = 0; j < 64; j += 4) {
        s0 += pp[(j + 0) * 256];
        s1 += pp[(j + 1) * 256];
        s2 += pp[(j + 2) * 256];
        s3 += pp[(j + 3) * 256];
    }
    red[(pg << 6) + t4] = (s0 + s1) + (s2 + s3);
    __syncthreads();

    if (t < 64) {
        const float val = (red[t4] + red[64 + t4] + red[128 + t4] + red[192 + t4]) * scale;
        float sq = val * val;                // e = el & 15 = t4 & 15
        sq += __shfl_xor(sq, 1);
        sq += __shfl_xor(sq, 2);
        sq += __shfl_xor(sq, 4);
        sq += __shfl_xor(sq, 8);
        const float f = sq / ((1.0f + sq) * sqrtf(sq + EPS));
        float v = val * f;
        if (vprev) v += vprev[(b << 8) + el];
        vout[(b << 8) + el] = v;
    }
    __syncthreads();
}

// XCD-bijective tile mapping for 512 blocks: physical XCD = bid&7; each XCD
// owns a contiguous 32-chunk p-range (2 MB of W -> L2-resident) and both
// batch-group duplicates of a p run on the same XCD.
__device__ __forceinline__ void tile_map(int bid, int& p, int& b0, int& i0) {
    const int xcd = bid & 7;
    const int j   = bid >> 3;               // 0..63
    p  = xcd * PPX + (j & (PPX - 1));       // bijective: 8 x 32 x 2 = 512
    b0 = (j >> 5) * BSET;                   // 0..1 batch groups
    i0 = p * IB;
}

// Stage x[b0..b0+31][i0..i0+7][0..7] -> smem [bl][il][d] (512 float4).
__device__ __forceinline__ void stage_x(float* smem, const float* __restrict__ x,
                                        int b0, int i0, int t) {
    #pragma unroll
    for (int j = 0; j < 2; ++j) {
        const int f  = t + (j << 8);        // 0..511
        const int bl = f >> 4;              // 0..31
        const int r  = f & 15;              // float4 within the bl row
        ((float4*)smem)[f] = *(const float4*)(x + ((size_t)(b0 + bl) * In + i0) * Dk + (r << 2));
    }
}

// ---------------- fused cooperative kernel (9 KB LDS) ----------------
__global__ __launch_bounds__(THREADS)
void caps_fused(const float* __restrict__ x, const float* __restrict__ W,
                float* __restrict__ partial, float* __restrict__ v0,
                float* __restrict__ vs, float* __restrict__ out)
{
    cg::grid_group grid = cg::this_grid();
    __shared__ __align__(16) float smem[2304];   // x [0,2048) | red [2048,2304)

    const int t = threadIdx.x, bid = blockIdx.x;
    int p, b0, i0;
    tile_map(bid, p, b0, i0);

    stage_x(smem, x, b0, i0, t);        // once, reused by all 3 iterations
    __syncthreads();

    // Reduce workers: even blocks only (rb = bid>>1) -> the 256 workers are
    // spread one-per-CU instead of stacked 2-per-CU.

    // r = 0: uniform coupling (1/16 folded into reduce scale)
    iter_body<true>(smem, W, nullptr, partial, p, b0, i0, t);
    grid.sync();
    if (!(bid & 1)) reduce_phase(smem + 2048, partial, 1.0f / 16.0f, nullptr, v0, bid >> 1, t);
    grid.sync();

    // r = 1: logits = dot(u_hat, v0);  vs = v0 + v1
    iter_body<false>(smem, W, v0, partial, p, b0, i0, t);
    grid.sync();
    if (!(bid & 1)) reduce_phase(smem + 2048, partial, 1.0f, v0, vs, bid >> 1, t);
    grid.sync();

    // r = 2: logits = dot(u_hat, v0 + v1); final squash -> out
    iter_body<false>(smem, W, vs, partial, p, b0, i0, t);
    grid.sync();
    if (!(bid & 1)) reduce_phase(smem + 2048, partial, 1.0f, nullptr, out, bid >> 1, t);
}

// ---------------- fallback: same phases as separate kernels ----------------
template<bool UNIFORM>
__global__ __launch_bounds__(THREADS)
void caps_iter_g(const float* __restrict__ x, const float* __restrict__ W,
                 const float* __restrict__ vsg, float* __restrict__ partial)
{
    __shared__ __align__(16) float smem[2048];
    const int t = threadIdx.x;
    int p, b0, i0;
    tile_map(blockIdx.x, p, b0, i0);
    stage_x(smem, x, b0, i0, t);
    __syncthreads();
    iter_body<UNIFORM>(smem, W, vsg, partial, p, b0, i0, t);
}

__global__ __launch_bounds__(THREADS)
void caps_reduce_g(const float* __restrict__ partial, float scale,
                   const float* __restrict__ vprev, float* __restrict__ vout)
{
    __shared__ __align__(16) float red[256];
    reduce_phase(red, partial, scale, vprev, vout, blockIdx.x, threadIdx.x);
}

extern "C" void kernel_launch(void* const* d_in, const int* in_sizes, int n_in,
                              void* d_out, int out_size, void* d_ws, size_t ws_size,
                              hipStream_t stream) {
    const float* x = (const float*)d_in[0];   // [64, 2048, 8]
    const float* W = (const float*)d_in[1];   // [2048, 16, 8, 16]
    float* out = (float*)d_out;               // [64, 16, 16]
    float* ws  = (float*)d_ws;

    float* v0      = ws;                      // [64,16,16]
    float* vs      = ws + 16384;              // v0 + v1
    float* partial = ws + 32768;              // [64][256][256] = 16.8 MB

    // Host-side co-residency gate (capture-safe: no stream ops). Only launch
    // cooperatively if the runtime agrees all 512 blocks fit.
    int dev = 0;
    hipGetDevice(&dev);
    int numCU = 0;
    hipDeviceGetAttribute(&numCU, hipDeviceAttributeMultiprocessorCount, dev);
    int maxB = 0;
    hipError_t oe = hipOccupancyMaxActiveBlocksPerMultiprocessor(
        &maxB, (const void*)caps_fused, THREADS, 0);
    const bool coop = (oe == hipSuccess) && numCU > 0 &&
                      ((long)maxB * numCU >= BLOCKS);

    if (coop) {
        void* args[] = { (void*)&x, (void*)&W, (void*)&partial,
                         (void*)&v0, (void*)&vs, (void*)&out };
        hipLaunchCooperativeKernel((void*)caps_fused, dim3(BLOCKS), dim3(THREADS),
                                   args, 0, stream);
    } else {
        caps_iter_g<true ><<<BLOCKS, THREADS, 0, stream>>>(x, W, nullptr, partial);
        caps_reduce_g<<<256, THREADS, 0, stream>>>(partial, 1.0f / 16.0f, nullptr, v0);
        caps_iter_g<false><<<BLOCKS, THREADS, 0, stream>>>(x, W, v0, partial);
        caps_reduce_g<<<256, THREADS, 0, stream>>>(partial, 1.0f, v0, vs);
        caps_iter_g<false><<<BLOCKS, THREADS, 0, stream>>>(x, W, vs, partial);
        caps_reduce_g<<<256, THREADS, 0, stream>>>(partial, 1.0f, nullptr, out);
    }
}

// Round 14
// 64.246 us; speedup vs baseline: 1.0668x; 1.0668x over previous
//
#include <hip/hip_runtime.h>
#include <hip/hip_cooperative_groups.h>
#include <cstddef>

namespace cg = cooperative_groups;

// Problem constants (from reference)
constexpr int Bn = 64;     // batch
constexpr int In = 2048;   // input capsules
constexpr int Dk = 8;      // input dim
constexpr int Kc = 16;     // output capsules
constexpr int En = 16;     // output dim
constexpr float EPS = 1e-7f;

// Decomposition (R8/R12 measured optimum; R9/R11/R13 sweeps all worse):
// block = (p, g) tile of 8 i's x 16 batches, 4 waves; wave owns 4 batches x
// all 8 i's -> disjoint outputs, barrier-free iter. 1024 blocks co-resident.
constexpr int IB   = 8;            // i's per block
constexpr int P    = In / IB;      // 256 i-chunks
constexpr int BSET = 16;           // batches per block (4 per wave)
constexpr int NBG  = Bn / BSET;    // 4 batch groups
constexpr int BLOCKS = P * NBG;    // 1024
constexpr int THREADS = 256;       // 4 waves
constexpr int PPX  = P / 8;        // 32 p-chunks per XCD (2 MB of W < 4 MB L2)

// Packed fp32 pair -> v_pk_fma_f32 (CDNA dual fp32 pipe). All pk values are
// lo/hi halves of float4s, statically indexed (rule-#20-safe).
typedef float v2f __attribute__((ext_vector_type(2)));
__device__ __forceinline__ v2f fma2(v2f a, v2f b, v2f c) {
    return __builtin_elementwise_fma(a, b, c);
}
__device__ __forceinline__ v2f splat2(float s) { return (v2f){s, s}; }

// DPP cross-lane add on the VALU pipe (no LDS-pipe traffic).
// ctrl: 0xB1 = quad_perm xor1, 0x4E = quad_perm xor2, 0x124/0x128 = row_ror 4/8
template<int CTRL>
__device__ __forceinline__ float dpp_add(float v) {
    int r = __builtin_amdgcn_update_dpp(0, __float_as_int(v), CTRL, 0xF, 0xF, true);
    return v + __int_as_float(r);
}

// One routing iteration for a (p, g) tile. x tile staged in smemx[0,1024) as
// [bl][il][d]. Wave wvi handles batches bw..bw+3 across all 8 i's.
// Arithmetic in v2f pairs so the backend emits v_pk_fma_f32 (2 FMA/instr):
// u_hat (16 pk), logit dot (2 pk), acc (8 pk) -- ~40% fewer VALU issues than
// the scalar form that plateaued R8-R13 at ~64 us.
template<bool UNIFORM>
__device__ __forceinline__ void iter_body(const float* __restrict__ smemx,
        const float* __restrict__ W, const float* __restrict__ vsg,
        float* __restrict__ partial, int p, int b0, int i0, int t)
{
    const int lane = t & 63;
    const int wvi  = t >> 6;                // 0..3
    const int k    = lane >> 2;             // output capsule
    const int e4   = (lane & 3) << 2;       // first of 4 output dims
    const int bw   = b0 + (wvi << 2);       // this wave's first batch

    v2f vlo[4], vhi[4];
    if (!UNIFORM) {
        #pragma unroll
        for (int b4 = 0; b4 < 4; ++b4) {
            const float4 vv = *(const float4*)(vsg + ((bw + b4) << 8) + k * 16 + e4);
            vlo[b4] = (v2f){vv.x, vv.y};
            vhi[b4] = (v2f){vv.z, vv.w};
        }
    }

    v2f alo[4], ahi[4];
    #pragma unroll
    for (int b4 = 0; b4 < 4; ++b4) { alo[b4] = (v2f){0.f, 0.f}; ahi[b4] = (v2f){0.f, 0.f}; }

    #pragma unroll 2
    for (int ii = 0; ii < IB; ++ii) {
        const int i = i0 + ii;
        const float* wp = W + (size_t)i * (Kc * Dk * En) + k * (Dk * En) + e4;
        v2f wlo[8], whi[8];
        #pragma unroll
        for (int d = 0; d < 8; ++d) {
            const float4 wv = *(const float4*)(wp + d * En);
            wlo[d] = (v2f){wv.x, wv.y};
            whi[d] = (v2f){wv.z, wv.w};
        }

        #pragma unroll
        for (int b4 = 0; b4 < 4; ++b4) {
            const int bl = (wvi << 2) + b4;
            const float* xp = smemx + (((bl << 3) + ii) << 3);  // [bl][ii][*]
            const float4 x0 = *(const float4*)xp;
            const float4 x1 = *(const float4*)(xp + 4);
            const float xs8[8] = {x0.x, x0.y, x0.z, x0.w, x1.x, x1.y, x1.z, x1.w};

            v2f ulo = (v2f){0.f, 0.f}, uhi = (v2f){0.f, 0.f};
            #pragma unroll
            for (int d = 0; d < 8; ++d) {
                const v2f xd = splat2(xs8[d]);
                ulo = fma2(xd, wlo[d], ulo);    // v_pk_fma_f32
                uhi = fma2(xd, whi[d], uhi);
            }

            if (UNIFORM) {
                alo[b4] += ulo;                 // v_pk_add_f32
                ahi[b4] += uhi;
            } else {
                v2f t2 = ulo * vlo[b4];         // v_pk_mul_f32
                t2 = fma2(uhi, vhi[b4], t2);
                float tt = t2.x + t2.y;         // full e4-dot
                tt = dpp_add<0xB1>(tt);         // e-reduce: quad xor 1
                tt = dpp_add<0x4E>(tt);         // e-reduce: quad xor 2
                const float pe = __expf(tt);    // no max-sub: |tt| small
                float den = dpp_add<0x124>(pe); // k-sum in row: ror 4
                den = dpp_add<0x128>(den);      // k-sum in row: ror 8
                den += __shfl_xor(den, 16);     // cross-row
                den += __shfl_xor(den, 32);
                const float c = pe * __builtin_amdgcn_rcpf(den);
                const v2f cc = splat2(c);
                alo[b4] = fma2(cc, ulo, alo[b4]);
                ahi[b4] = fma2(cc, uhi, ahi[b4]);
            }
        }
    }

    #pragma unroll
    for (int b4 = 0; b4 < 4; ++b4) {
        *(float4*)(partial + ((size_t)(bw + b4) * P + p) * 256 + k * 16 + e4) =
            make_float4(alo[b4].x, alo[b4].y, ahi[b4].x, ahi[b4].y);
    }
}

// Sum the P=256 partials, squash, optional vprev add. rb = 0..255:
// b = rb>>2, element-quarter q = rb&3; 4 p-groups of 64 p's, combined in LDS.
__device__ __forceinline__ void reduce_phase(float* red,
        const float* __restrict__ partial, float scale,
        const float* __restrict__ vprev, float* __restrict__ vout, int rb, int t)
{
    const int b  = rb >> 2;
    const int q  = rb & 3;
    const int t4 = t & 63;
    const int pg = t >> 6;
    const int el = (q << 6) + t4;           // element 0..255 (= k*16+e)
    const float* pp = partial + (size_t)b * (P * 256) + ((pg << 6) * 256) + el;

    float s0 = 0.f, s1 = 0.f, s2 = 0.f, s3 = 0.f;
    #pragma unroll 4
    for (int j = 0; j < 64; j += 4) {
        s0 += pp[(j + 0) * 256];
        s1 += pp[(j + 1) * 256];
        s2 += pp[(j + 2) * 256];
        s3 += pp[(j + 3) * 256];
    }
    red[(pg << 6) + t4] = (s0 + s1) + (s2 + s3);
    __syncthreads();

    if (t < 64) {
        const float val = (red[t4] + red[64 + t4] + red[128 + t4] + red[192 + t4]) * scale;
        float sq = val * val;                // e = el & 15 = t4 & 15
        sq += __shfl_xor(sq, 1);
        sq += __shfl_xor(sq, 2);
        sq += __shfl_xor(sq, 4);
        sq += __shfl_xor(sq, 8);
        const float f = sq / ((1.0f + sq) * sqrtf(sq + EPS));
        float v = val * f;
        if (vprev) v += vprev[(b << 8) + el];
        vout[(b << 8) + el] = v;
    }
    __syncthreads();
}

// XCD-bijective tile mapping: physical XCD = bid&7 (round-robin dispatch);
// each XCD owns a contiguous 32-chunk p-range (2 MB of W -> L2-resident) and
// all 4 batch-group duplicates of a p run on the same XCD.
__device__ __forceinline__ void tile_map(int bid, int& p, int& b0, int& i0) {
    const int xcd = bid & 7;
    const int j   = bid >> 3;               // 0..127
    p  = xcd * PPX + (j & (PPX - 1));       // bijective: 8 x 32 x 4 = 1024
    b0 = (j >> 5) * BSET;                   // 0..3 batch groups
    i0 = p * IB;
}

// Stage x[b0..b0+15][i0..i0+7][0..7] -> smem [bl][il][d] (256 float4).
__device__ __forceinline__ void stage_x(float* smem, const float* __restrict__ x,
                                        int b0, int i0, int t) {
    const int bl = t >> 4;                  // 0..15
    const int r  = t & 15;                  // float4 within the bl row
    ((float4*)smem)[t] = *(const float4*)(x + ((size_t)(b0 + bl) * In + i0) * Dk + (r << 2));
}

// ---------------- fused cooperative kernel (5 KB LDS) ----------------
__global__ __launch_bounds__(THREADS)
void caps_fused(const float* __restrict__ x, const float* __restrict__ W,
                float* __restrict__ partial, float* __restrict__ v0,
                float* __restrict__ vs, float* __restrict__ out)
{
    cg::grid_group grid = cg::this_grid();
    __shared__ __align__(16) float smem[1280];   // x [0,1024) | red [1024,1280)

    const int t = threadIdx.x, bid = blockIdx.x;
    int p, b0, i0;
    tile_map(bid, p, b0, i0);

    stage_x(smem, x, b0, i0, t);        // once, reused by all 3 iterations
    __syncthreads();

    // r = 0: uniform coupling (1/16 folded into reduce scale)
    iter_body<true>(smem, W, nullptr, partial, p, b0, i0, t);
    grid.sync();
    if (bid < 256) reduce_phase(smem + 1024, partial, 1.0f / 16.0f, nullptr, v0, bid, t);
    grid.sync();

    // r = 1: logits = dot(u_hat, v0);  vs = v0 + v1
    iter_body<false>(smem, W, v0, partial, p, b0, i0, t);
    grid.sync();
    if (bid < 256) reduce_phase(smem + 1024, partial, 1.0f, v0, vs, bid, t);
    grid.sync();

    // r = 2: logits = dot(u_hat, v0 + v1); final squash -> out
    iter_body<false>(smem, W, vs, partial, p, b0, i0, t);
    grid.sync();
    if (bid < 256) reduce_phase(smem + 1024, partial, 1.0f, nullptr, out, bid, t);
}

// ---------------- fallback: same phases as separate kernels ----------------
template<bool UNIFORM>
__global__ __launch_bounds__(THREADS)
void caps_iter_g(const float* __restrict__ x, const float* __restrict__ W,
                 const float* __restrict__ vsg, float* __restrict__ partial)
{
    __shared__ __align__(16) float smem[1024];
    const int t = threadIdx.x;
    int p, b0, i0;
    tile_map(blockIdx.x, p, b0, i0);
    stage_x(smem, x, b0, i0, t);
    __syncthreads();
    iter_body<UNIFORM>(smem, W, vsg, partial, p, b0, i0, t);
}

__global__ __launch_bounds__(THREADS)
void caps_reduce_g(const float* __restrict__ partial, float scale,
                   const float* __restrict__ vprev, float* __restrict__ vout)
{
    __shared__ __align__(16) float red[256];
    reduce_phase(red, partial, scale, vprev, vout, blockIdx.x, threadIdx.x);
}

extern "C" void kernel_launch(void* const* d_in, const int* in_sizes, int n_in,
                              void* d_out, int out_size, void* d_ws, size_t ws_size,
                              hipStream_t stream) {
    const float* x = (const float*)d_in[0];   // [64, 2048, 8]
    const float* W = (const float*)d_in[1];   // [2048, 16, 8, 16]
    float* out = (float*)d_out;               // [64, 16, 16]
    float* ws  = (float*)d_ws;

    float* v0      = ws;                      // [64,16,16]
    float* vs      = ws + 16384;              // v0 + v1
    float* partial = ws + 32768;              // [64][256][256] = 16.8 MB

    // Host-side co-residency gate (capture-safe: no stream ops). Only launch
    // cooperatively if the runtime agrees all 1024 blocks fit.
    int dev = 0;
    hipGetDevice(&dev);
    int numCU = 0;
    hipDeviceGetAttribute(&numCU, hipDeviceAttributeMultiprocessorCount, dev);
    int maxB = 0;
    hipError_t oe = hipOccupancyMaxActiveBlocksPerMultiprocessor(
        &maxB, (const void*)caps_fused, THREADS, 0);
    const bool coop = (oe == hipSuccess) && numCU > 0 &&
                      ((long)maxB * numCU >= BLOCKS);

    if (coop) {
        void* args[] = { (void*)&x, (void*)&W, (void*)&partial,
                         (void*)&v0, (void*)&vs, (void*)&out };
        hipLaunchCooperativeKernel((void*)caps_fused, dim3(BLOCKS), dim3(THREADS),
                                   args, 0, stream);
    } else {
        caps_iter_g<true ><<<BLOCKS, THREADS, 0, stream>>>(x, W, nullptr, partial);
        caps_reduce_g<<<256, THREADS, 0, stream>>>(partial, 1.0f / 16.0f, nullptr, v0);
        caps_iter_g<false><<<BLOCKS, THREADS, 0, stream>>>(x, W, v0, partial);
        caps_reduce_g<<<256, THREADS, 0, stream>>>(partial, 1.0f, v0, vs);
        caps_iter_g<false><<<BLOCKS, THREADS, 0, stream>>>(x, W, vs, partial);
        caps_reduce_g<<<256, THREADS, 0, stream>>>(partial, 1.0f, nullptr, out);
    }
}